// Round 9
// baseline (228.008 us; speedup 1.0000x reference)
//
#include <hip/hip_runtime.h>
#include <cstdint>
#include <cstddef>

#define D 64
#define D_FEAT 128
#define SLOPE 0.01f
#define BSH 7                 // bucket = dst >> 7  (128 nodes per bucket)
#define BW 128
#define CAP 2560              // per-bucket slot capacity (mean 2046, +11 sigma)

typedef __attribute__((ext_vector_type(8))) short bf16x8;
typedef __attribute__((ext_vector_type(4))) float f32x4;

struct P7 { const float* w[7]; };

__device__ __forceinline__ float leaky(float v) { return v >= 0.f ? v : SLOPE * v; }

__device__ __forceinline__ unsigned short f2bf(float f) {
    union { float f; unsigned u; } v; v.f = f;
    unsigned r = v.u + 0x7FFF + ((v.u >> 16) & 1);   // RNE
    return (unsigned short)(r >> 16);
}
__device__ __forceinline__ float bf2f(unsigned short b) {
    union { unsigned u; float f; } v; v.u = ((unsigned)b) << 16;
    return v.f;
}

// ---------------- prep: weights fp32 row-major -> bf16 col-major; + gcur init --
// blocks 0..6 = matrices (0: K=128, 1..6: K=64); block 7 inits gcur.
__global__ __launch_bounds__(256) void k_prep(P7 p, unsigned short* __restrict__ out,
    int* __restrict__ gcur, int nbk)
{
    int m = blockIdx.x;
    if (m == 7) {
        for (int i = threadIdx.x; i < nbk; i += 256) gcur[i] = i * CAP;
        return;
    }
    int K = (m == 0) ? 128 : 64;
    const float* W = p.w[m];
    unsigned short* o = out + ((m == 0) ? 0 : 8192 + (m - 1) * 4096);
    int total = K * 64;
    for (int i = threadIdx.x; i < total; i += 256) {
        int col = i / K, k = i - col * K;
        o[i] = f2bf(W[k * 64 + col]);     // o[col*K + k]
    }
}

// ---------------- partition edges into strided buckets, packed (dloc<<25|src) --
__global__ __launch_bounds__(256) void k_part(const int* __restrict__ esrc,
    const int* __restrict__ edst, int* __restrict__ gcur,
    unsigned* __restrict__ pairs, int E)
{
    __shared__ int lcnt[1024];
    __shared__ int lbase[1024];
    int base = blockIdx.x * 4096;
    for (int i = threadIdx.x; i < 1024; i += 256) lcnt[i] = 0;
    __syncthreads();
    int dv[16];
#pragma unroll
    for (int i = 0; i < 16; ++i) {
        int e = base + i * 256 + threadIdx.x;
        if (e < E) {
            dv[i] = edst[e];
            atomicAdd(&lcnt[dv[i] >> BSH], 1);
        } else dv[i] = -1;
    }
    __syncthreads();
    for (int i = threadIdx.x; i < 1024; i += 256) {
        int c = lcnt[i];
        lbase[i] = c ? atomicAdd(&gcur[i], c) : 0;
    }
    __syncthreads();
    for (int i = threadIdx.x; i < 1024; i += 256) lcnt[i] = 0;
    __syncthreads();
#pragma unroll
    for (int i = 0; i < 16; ++i) {
        if (dv[i] >= 0) {
            int e = base + i * 256 + threadIdx.x;
            int b = dv[i] >> BSH;
            int r = atomicAdd(&lcnt[b], 1);
            unsigned pk = ((unsigned)(dv[i] & (BW - 1)) << 25) | (unsigned)esrc[e];
            pairs[lbase[b] + r] = pk;
        }
    }
}

// ---------------- per-bucket counting sort -> per-node ranges (coalesced) ------
__global__ __launch_bounds__(256) void k_sort(const unsigned* __restrict__ pairs,
    const int* __restrict__ gcur, int* __restrict__ nstart, int* __restrict__ nend,
    int* __restrict__ srcs, int N)
{
    __shared__ int lh[BW];
    __shared__ int cur[BW];
    __shared__ unsigned buf[CAP];
    int b = blockIdx.x;
    int node0 = b << BSH;
    int s0 = b * CAP;
    int cnt = gcur[b] - s0;
    if (threadIdx.x < BW) lh[threadIdx.x] = 0;
    __syncthreads();
    for (int i = threadIdx.x; i < cnt; i += 256)
        atomicAdd(&lh[pairs[s0 + i] >> 25], 1);
    __syncthreads();
    if (threadIdx.x < 64) {   // wave 0: exclusive scan of 128 counts, 2/lane
        int a = lh[2 * threadIdx.x], c = lh[2 * threadIdx.x + 1];
        int s = a + c, inc = s;
#pragma unroll
        for (int d = 1; d < 64; d <<= 1) {
            int u = __shfl_up(inc, d);
            if ((int)threadIdx.x >= d) inc += u;
        }
        int ex = inc - s;
        cur[2 * threadIdx.x] = ex;
        cur[2 * threadIdx.x + 1] = ex + a;
    }
    __syncthreads();
    if (threadIdx.x < BW) {
        int node = node0 + threadIdx.x;
        if (node < N) {
            nstart[node] = s0 + cur[threadIdx.x];
            nend[node]   = s0 + cur[threadIdx.x] + lh[threadIdx.x];
        }
    }
    __syncthreads();
    for (int i = threadIdx.x; i < cnt; i += 256) {
        unsigned p = pairs[s0 + i];
        int r = atomicAdd(&cur[p >> 25], 1);
        buf[r] = p & 0x1FFFFFFu;
    }
    __syncthreads();
    for (int i = threadIdx.x; i < cnt; i += 256)
        srcs[s0 + i] = (int)buf[i];
}

// ---------------- MLP + L2 norm (MFMA), fp32 in -> bf16 out ----------------
// Wt: bf16 col-major [64][128]
__global__ __launch_bounds__(256) void k_mlp(const float* __restrict__ F,
    const unsigned short* __restrict__ Wt, const float* __restrict__ bm,
    unsigned short* __restrict__ Xb, int N)
{
    int lane = threadIdx.x & 63, w = threadIdx.x >> 6;
    int cl = lane & 15, g = lane >> 4;
    int ntiles = (N + 63) / 64;

    bf16x8 Wmf[4][4];
#pragma unroll
    for (int ks = 0; ks < 4; ++ks)
#pragma unroll
        for (int nt = 0; nt < 4; ++nt)
            Wmf[ks][nt] = *(const bf16x8*)(Wt + (nt * 16 + cl) * 128 + ks * 32 + g * 8);
    float bmv[4];
#pragma unroll
    for (int nt = 0; nt < 4; ++nt) bmv[nt] = bm[nt * 16 + cl];

    for (int tb = blockIdx.x; tb < ntiles; tb += gridDim.x) {
        int node0 = tb * 64 + w * 16;
        if (node0 >= N) continue;
        f32x4 acc[4];
#pragma unroll
        for (int nt = 0; nt < 4; ++nt) acc[nt] = (f32x4){0.f, 0.f, 0.f, 0.f};
#pragma unroll
        for (int ks = 0; ks < 4; ++ks) {
            const float4* fp = (const float4*)(F + (size_t)(node0 + cl) * D_FEAT + ks * 32 + g * 8);
            float4 a = fp[0], b = fp[1];
            bf16x8 af;
            af[0] = (short)f2bf(a.x); af[1] = (short)f2bf(a.y);
            af[2] = (short)f2bf(a.z); af[3] = (short)f2bf(a.w);
            af[4] = (short)f2bf(b.x); af[5] = (short)f2bf(b.y);
            af[6] = (short)f2bf(b.z); af[7] = (short)f2bf(b.w);
#pragma unroll
            for (int nt = 0; nt < 4; ++nt)
                acc[nt] = __builtin_amdgcn_mfma_f32_16x16x32_bf16(af, Wmf[ks][nt], acc[nt], 0, 0, 0);
        }
        float ss[4] = {0.f, 0.f, 0.f, 0.f};
#pragma unroll
        for (int nt = 0; nt < 4; ++nt)
#pragma unroll
            for (int i = 0; i < 4; ++i) {
                float v = acc[nt][i] + bmv[nt];
                acc[nt][i] = v;
                ss[i] += v * v;
            }
#pragma unroll
        for (int off = 8; off >= 1; off >>= 1)
#pragma unroll
            for (int i = 0; i < 4; ++i)
                ss[i] += __shfl_xor(ss[i], off);
        float inv[4];
#pragma unroll
        for (int i = 0; i < 4; ++i)
            inv[i] = 1.f / fmaxf(sqrtf(ss[i]), 1e-12f);
#pragma unroll
        for (int nt = 0; nt < 4; ++nt)
#pragma unroll
            for (int i = 0; i < 4; ++i)
                Xb[(size_t)(node0 + g * 4 + i) * D + nt * 16 + cl] = f2bf(acc[nt][i] * inv[i]);
    }
}

// ---------------- gather: Agg[n] = sum_{edges dst==n} Xb[src] ----------------
// eighth-wave per edge: 8 lanes x 16B (uint4) cover one 64xbf16 row; 8 edges/iter
__global__ __launch_bounds__(256) void k_gather(const int* __restrict__ nstart,
    const int* __restrict__ nend, const int* __restrict__ srcs,
    const unsigned short* __restrict__ Xb, unsigned short* __restrict__ Ab, int N)
{
    int lane = threadIdx.x & 63, w = threadIdx.x >> 6;
    int node = blockIdx.x * 4 + w;
    if (node >= N) return;
    int start = nstart[node];
    int end = nend[node];
    int g = lane >> 3;          // 8 groups of 8 lanes, one edge each
    int li = lane & 7;          // li covers cols [li*8, li*8+8)
    float acc[8] = {0.f, 0.f, 0.f, 0.f, 0.f, 0.f, 0.f, 0.f};
    for (int base = start; base < end; base += 64) {
        int m = end - base; if (m > 64) m = 64;
        int sid = (base + lane < end) ? srcs[base + lane] : 0;
        int iters = (m + 7) >> 3;
        for (int j = 0; j < iters; ++j) {
            int idx = (j << 3) | g;
            int s = __shfl(sid, idx);
            if (idx < m) {
                uint4 u = *(const uint4*)(Xb + (size_t)s * D + li * 8);
                acc[0] += bf2f((unsigned short)(u.x & 0xFFFFu));
                acc[1] += bf2f((unsigned short)(u.x >> 16));
                acc[2] += bf2f((unsigned short)(u.y & 0xFFFFu));
                acc[3] += bf2f((unsigned short)(u.y >> 16));
                acc[4] += bf2f((unsigned short)(u.z & 0xFFFFu));
                acc[5] += bf2f((unsigned short)(u.z >> 16));
                acc[6] += bf2f((unsigned short)(u.w & 0xFFFFu));
                acc[7] += bf2f((unsigned short)(u.w >> 16));
            }
        }
    }
#pragma unroll
    for (int d = 32; d >= 8; d >>= 1)
#pragma unroll
        for (int i = 0; i < 8; ++i)
            acc[i] += __shfl_xor(acc[i], d);
    if (g == 0) {
        uint4 o;
        o.x = (unsigned)f2bf(acc[0]) | ((unsigned)f2bf(acc[1]) << 16);
        o.y = (unsigned)f2bf(acc[2]) | ((unsigned)f2bf(acc[3]) << 16);
        o.z = (unsigned)f2bf(acc[4]) | ((unsigned)f2bf(acc[5]) << 16);
        o.w = (unsigned)f2bf(acc[6]) | ((unsigned)f2bf(acc[7]) << 16);
        *(uint4*)(Ab + (size_t)node * D + li * 8) = o;
    }
}

// ---------------- fused combine (MFMA):
// O = leaky( leaky(Agg@Wc)@Wg + bg + leaky(X@Wl + bl) + ID ) ----------------
// Wct/Wlt/Wgt: bf16 col-major [64][64]
__global__ __launch_bounds__(256) void k_combine(
    const unsigned short* Xb, const unsigned short* __restrict__ Ab,
    const unsigned short* __restrict__ Wct,
    const unsigned short* __restrict__ Wlt, const float* __restrict__ bl,
    const unsigned short* __restrict__ Wgt, const float* __restrict__ bg,
    const float* __restrict__ ID,
    unsigned short* Ob, float* Of, int N)
{
    __shared__ unsigned short tl[4][16][72];
    int lane = threadIdx.x & 63, w = threadIdx.x >> 6;
    int cl = lane & 15, g = lane >> 4;
    int ntiles = (N + 63) / 64;

    bf16x8 Wcf[2][4], Wlf[2][4], Wgf[2][4];
#pragma unroll
    for (int ks = 0; ks < 2; ++ks)
#pragma unroll
        for (int nt = 0; nt < 4; ++nt) {
            int off = (nt * 16 + cl) * 64 + ks * 32 + g * 8;
            Wcf[ks][nt] = *(const bf16x8*)(Wct + off);
            Wlf[ks][nt] = *(const bf16x8*)(Wlt + off);
            Wgf[ks][nt] = *(const bf16x8*)(Wgt + off);
        }
    float blv[4], bgv[4];
#pragma unroll
    for (int nt = 0; nt < 4; ++nt) {
        blv[nt] = bl[nt * 16 + cl];
        bgv[nt] = bg[nt * 16 + cl];
    }

    for (int tb = blockIdx.x; tb < ntiles; tb += gridDim.x) {
        int node0 = tb * 64 + w * 16;
        bool active = node0 < N;
        f32x4 accL[4], accG[4];
        if (active) {
            const bf16x8* xr = (const bf16x8*)(Xb + (size_t)(node0 + cl) * D + g * 8);
            const bf16x8* ar = (const bf16x8*)(Ab + (size_t)(node0 + cl) * D + g * 8);
            bf16x8 xf0 = xr[0], xf1 = xr[4];
            bf16x8 af0 = ar[0], af1 = ar[4];
            f32x4 accC[4];
#pragma unroll
            for (int nt = 0; nt < 4; ++nt) {
                f32x4 z = (f32x4){0.f, 0.f, 0.f, 0.f};
                accL[nt] = __builtin_amdgcn_mfma_f32_16x16x32_bf16(xf1, Wlf[1][nt],
                            __builtin_amdgcn_mfma_f32_16x16x32_bf16(xf0, Wlf[0][nt], z, 0, 0, 0), 0, 0, 0);
                accC[nt] = __builtin_amdgcn_mfma_f32_16x16x32_bf16(af1, Wcf[1][nt],
                            __builtin_amdgcn_mfma_f32_16x16x32_bf16(af0, Wcf[0][nt], z, 0, 0, 0), 0, 0, 0);
            }
#pragma unroll
            for (int nt = 0; nt < 4; ++nt)
#pragma unroll
                for (int i = 0; i < 4; ++i)
                    tl[w][g * 4 + i][nt * 16 + cl] = f2bf(leaky(accC[nt][i]));
        }
        __syncthreads();
        if (active) {
            const bf16x8* tr = (const bf16x8*)&tl[w][cl][g * 8];
            bf16x8 tf0 = tr[0], tf1 = tr[4];
#pragma unroll
            for (int nt = 0; nt < 4; ++nt) {
                f32x4 z = (f32x4){0.f, 0.f, 0.f, 0.f};
                accG[nt] = __builtin_amdgcn_mfma_f32_16x16x32_bf16(tf1, Wgf[1][nt],
                            __builtin_amdgcn_mfma_f32_16x16x32_bf16(tf0, Wgf[0][nt], z, 0, 0, 0), 0, 0, 0);
            }
#pragma unroll
            for (int nt = 0; nt < 4; ++nt) {
                int col = nt * 16 + cl;
#pragma unroll
                for (int i = 0; i < 4; ++i) {
                    size_t row = (size_t)(node0 + g * 4 + i);
                    float xh = leaky(accL[nt][i] + blv[nt]) + ID[row * D + col];
                    float o = leaky(accG[nt][i] + bgv[nt] + xh);
                    if (Ob) Ob[row * D + col] = f2bf(o);
                    else    Of[row * D + col] = o;
                }
            }
        }
        __syncthreads();
    }
}

extern "C" void kernel_launch(void* const* d_in, const int* in_sizes, int n_in,
                              void* d_out, int out_size, void* d_ws, size_t ws_size,
                              hipStream_t stream)
{
    const float* features = (const float*)d_in[0];
    const float* id_emb   = (const float*)d_in[1];
    const int*   eidx     = (const int*)d_in[2];
    const float* W_mlp    = (const float*)d_in[3];
    const float* b_mlp    = (const float*)d_in[4];
    const float* Wc1 = (const float*)d_in[5];
    const float* Wl1 = (const float*)d_in[6];
    const float* bl1 = (const float*)d_in[7];
    const float* Wg1 = (const float*)d_in[8];
    const float* bg1 = (const float*)d_in[9];
    const float* Wc2 = (const float*)d_in[10];
    const float* Wl2 = (const float*)d_in[11];
    const float* bl2 = (const float*)d_in[12];
    const float* Wg2 = (const float*)d_in[13];
    const float* bg2 = (const float*)d_in[14];

    int N = in_sizes[0] / D_FEAT;
    int E = in_sizes[2] / 2;
    const int* esrc = eidx;
    const int* edst = eidx + E;
    int nbk = (N + BW - 1) >> BSH;               // 782 for N=100000

    unsigned short* Xb = (unsigned short*)d_ws;  // [N][64] bf16
    unsigned short* Ab = Xb + (size_t)N * D;     // [N][64] bf16
    int* srcs   = (int*)(Ab + (size_t)N * D);    // [nbk*CAP] bucket-strided
    int* nstart = srcs + (size_t)nbk * CAP;      // [N]
    int* nend   = nstart + N;                    // [N]
    int* gcur   = nend + N;                      // [1024]
    unsigned short* wt = (unsigned short*)(gcur + 1024);  // 8192 + 6*4096 bf16
    unsigned short* Wmt  = wt;
    unsigned short* Wct1 = wt + 8192;
    unsigned short* Wlt1 = Wct1 + 4096;
    unsigned short* Wgt1 = Wlt1 + 4096;
    unsigned short* Wct2 = Wgt1 + 4096;
    unsigned short* Wlt2 = Wct2 + 4096;
    unsigned short* Wgt2 = Wlt2 + 4096;

    // pairs scratch lives in d_out (25.6 MB >= nbk*CAP*4 = 8.0 MB); fully dead
    // before the final combine writes d_out.
    unsigned* pairs = (unsigned*)d_out;

    dim3 blk(256);
    int ntiles = (N + 63) / 64;
    int egrid = (E + 4095) / 4096;

    P7 p7;
    p7.w[0] = W_mlp; p7.w[1] = Wc1; p7.w[2] = Wl1; p7.w[3] = Wg1;
    p7.w[4] = Wc2; p7.w[5] = Wl2; p7.w[6] = Wg2;

    // weight transpose + gcur init (one dispatch)
    k_prep<<<8, blk, 0, stream>>>(p7, wt, gcur, nbk);

    // bucket CSR build (shared by both layers)
    k_part<<<egrid, blk, 0, stream>>>(esrc, edst, gcur, pairs, E);
    k_sort<<<nbk, blk, 0, stream>>>(pairs, gcur, nstart, nend, srcs, N);

    k_mlp<<<ntiles, blk, 0, stream>>>(features, Wmt, b_mlp, Xb, N);

    // layer 1  (combine writes x1 bf16 in-place over Xb)
    k_gather <<<(N + 3) / 4, blk, 0, stream>>>(nstart, nend, srcs, Xb, Ab, N);
    k_combine<<<ntiles, blk, 0, stream>>>(Xb, Ab, Wct1, Wlt1, bl1, Wgt1, bg1, id_emb,
                                          Xb, (float*)nullptr, N);

    // layer 2
    k_gather <<<(N + 3) / 4, blk, 0, stream>>>(nstart, nend, srcs, Xb, Ab, N);
    k_combine<<<ntiles, blk, 0, stream>>>(Xb, Ab, Wct2, Wlt2, bl2, Wgt2, bg2, id_emb,
                                          (unsigned short*)nullptr, (float*)d_out, N);
}

// Round 10
// 178.156 us; speedup vs baseline: 1.2798x; 1.2798x over previous
//
#include <hip/hip_runtime.h>
#include <cstdint>
#include <cstddef>

#define D 64
#define D_FEAT 128
#define SLOPE 0.01f
#define BSH 7                 // bucket = dst >> 7  (128 nodes per bucket)
#define BW 128
#define CAP 2560              // per-bucket slot capacity (mean 2046, +11 sigma)
#define WS 72                 // LDS weight row stride (bf16): 144B, 16B-aligned, 2-way banks

typedef __attribute__((ext_vector_type(8))) short bf16x8;
typedef __attribute__((ext_vector_type(4))) float f32x4;

struct P7 { const float* w[7]; };

__device__ __forceinline__ float leaky(float v) { return v >= 0.f ? v : SLOPE * v; }

__device__ __forceinline__ unsigned short f2bf(float f) {
    union { float f; unsigned u; } v; v.f = f;
    unsigned r = v.u + 0x7FFF + ((v.u >> 16) & 1);   // RNE
    return (unsigned short)(r >> 16);
}
__device__ __forceinline__ float bf2f(unsigned short b) {
    union { unsigned u; float f; } v; v.u = ((unsigned)b) << 16;
    return v.f;
}

// ---------------- prep: weights fp32 row-major -> bf16 col-major; + gcur init --
// blocks 0..6 = matrices (0: K=128, 1..6: K=64); block 7 inits gcur.
__global__ __launch_bounds__(256) void k_prep(P7 p, unsigned short* __restrict__ out,
    int* __restrict__ gcur, int nbk)
{
    int m = blockIdx.x;
    if (m == 7) {
        for (int i = threadIdx.x; i < nbk; i += 256) gcur[i] = i * CAP;
        return;
    }
    int K = (m == 0) ? 128 : 64;
    const float* W = p.w[m];
    unsigned short* o = out + ((m == 0) ? 0 : 8192 + (m - 1) * 4096);
    int total = K * 64;
    for (int i = threadIdx.x; i < total; i += 256) {
        int col = i / K, k = i - col * K;
        o[i] = f2bf(W[k * 64 + col]);     // o[col*K + k]
    }
}

// ---------------- partition edges into strided buckets, packed (dloc<<25|src) --
__global__ __launch_bounds__(256) void k_part(const int* __restrict__ esrc,
    const int* __restrict__ edst, int* __restrict__ gcur,
    unsigned* __restrict__ pairs, int E)
{
    __shared__ int lcnt[1024];
    __shared__ int lbase[1024];
    int base = blockIdx.x * 4096;
    for (int i = threadIdx.x; i < 1024; i += 256) lcnt[i] = 0;
    __syncthreads();
    int dv[16];
#pragma unroll
    for (int i = 0; i < 16; ++i) {
        int e = base + i * 256 + threadIdx.x;
        if (e < E) {
            dv[i] = edst[e];
            atomicAdd(&lcnt[dv[i] >> BSH], 1);
        } else dv[i] = -1;
    }
    __syncthreads();
    for (int i = threadIdx.x; i < 1024; i += 256) {
        int c = lcnt[i];
        lbase[i] = c ? atomicAdd(&gcur[i], c) : 0;
    }
    __syncthreads();
    for (int i = threadIdx.x; i < 1024; i += 256) lcnt[i] = 0;
    __syncthreads();
#pragma unroll
    for (int i = 0; i < 16; ++i) {
        if (dv[i] >= 0) {
            int e = base + i * 256 + threadIdx.x;
            int b = dv[i] >> BSH;
            int r = atomicAdd(&lcnt[b], 1);
            unsigned pk = ((unsigned)(dv[i] & (BW - 1)) << 25) | (unsigned)esrc[e];
            pairs[lbase[b] + r] = pk;
        }
    }
}

// ---------------- per-bucket counting sort -> per-node ranges (coalesced) ------
__global__ __launch_bounds__(256) void k_sort(const unsigned* __restrict__ pairs,
    const int* __restrict__ gcur, int* __restrict__ nstart, int* __restrict__ nend,
    int* __restrict__ srcs, int N)
{
    __shared__ int lh[BW];
    __shared__ int cur[BW];
    __shared__ unsigned buf[CAP];
    int b = blockIdx.x;
    int node0 = b << BSH;
    int s0 = b * CAP;
    int cnt = gcur[b] - s0;
    if (threadIdx.x < BW) lh[threadIdx.x] = 0;
    __syncthreads();
    for (int i = threadIdx.x; i < cnt; i += 256)
        atomicAdd(&lh[pairs[s0 + i] >> 25], 1);
    __syncthreads();
    if (threadIdx.x < 64) {   // wave 0: exclusive scan of 128 counts, 2/lane
        int a = lh[2 * threadIdx.x], c = lh[2 * threadIdx.x + 1];
        int s = a + c, inc = s;
#pragma unroll
        for (int d = 1; d < 64; d <<= 1) {
            int u = __shfl_up(inc, d);
            if ((int)threadIdx.x >= d) inc += u;
        }
        int ex = inc - s;
        cur[2 * threadIdx.x] = ex;
        cur[2 * threadIdx.x + 1] = ex + a;
    }
    __syncthreads();
    if (threadIdx.x < BW) {
        int node = node0 + threadIdx.x;
        if (node < N) {
            nstart[node] = s0 + cur[threadIdx.x];
            nend[node]   = s0 + cur[threadIdx.x] + lh[threadIdx.x];
        }
    }
    __syncthreads();
    for (int i = threadIdx.x; i < cnt; i += 256) {
        unsigned p = pairs[s0 + i];
        int r = atomicAdd(&cur[p >> 25], 1);
        buf[r] = p & 0x1FFFFFFu;
    }
    __syncthreads();
    for (int i = threadIdx.x; i < cnt; i += 256)
        srcs[s0 + i] = (int)buf[i];
}

// ---------------- MLP + L2 norm (MFMA), fp32 in -> bf16 out ----------------
// Wt: bf16 col-major [64][128]
__global__ __launch_bounds__(256) void k_mlp(const float* __restrict__ F,
    const unsigned short* __restrict__ Wt, const float* __restrict__ bm,
    unsigned short* __restrict__ Xb, int N)
{
    int lane = threadIdx.x & 63, w = threadIdx.x >> 6;
    int cl = lane & 15, g = lane >> 4;
    int ntiles = (N + 63) / 64;

    bf16x8 Wmf[4][4];
#pragma unroll
    for (int ks = 0; ks < 4; ++ks)
#pragma unroll
        for (int nt = 0; nt < 4; ++nt)
            Wmf[ks][nt] = *(const bf16x8*)(Wt + (nt * 16 + cl) * 128 + ks * 32 + g * 8);
    float bmv[4];
#pragma unroll
    for (int nt = 0; nt < 4; ++nt) bmv[nt] = bm[nt * 16 + cl];

    for (int tb = blockIdx.x; tb < ntiles; tb += gridDim.x) {
        int node0 = tb * 64 + w * 16;
        if (node0 >= N) continue;
        f32x4 acc[4];
#pragma unroll
        for (int nt = 0; nt < 4; ++nt) acc[nt] = (f32x4){0.f, 0.f, 0.f, 0.f};
#pragma unroll
        for (int ks = 0; ks < 4; ++ks) {
            const float4* fp = (const float4*)(F + (size_t)(node0 + cl) * D_FEAT + ks * 32 + g * 8);
            float4 a = fp[0], b = fp[1];
            bf16x8 af;
            af[0] = (short)f2bf(a.x); af[1] = (short)f2bf(a.y);
            af[2] = (short)f2bf(a.z); af[3] = (short)f2bf(a.w);
            af[4] = (short)f2bf(b.x); af[5] = (short)f2bf(b.y);
            af[6] = (short)f2bf(b.z); af[7] = (short)f2bf(b.w);
#pragma unroll
            for (int nt = 0; nt < 4; ++nt)
                acc[nt] = __builtin_amdgcn_mfma_f32_16x16x32_bf16(af, Wmf[ks][nt], acc[nt], 0, 0, 0);
        }
        float ss[4] = {0.f, 0.f, 0.f, 0.f};
#pragma unroll
        for (int nt = 0; nt < 4; ++nt)
#pragma unroll
            for (int i = 0; i < 4; ++i) {
                float v = acc[nt][i] + bmv[nt];
                acc[nt][i] = v;
                ss[i] += v * v;
            }
#pragma unroll
        for (int off = 8; off >= 1; off >>= 1)
#pragma unroll
            for (int i = 0; i < 4; ++i)
                ss[i] += __shfl_xor(ss[i], off);
        float inv[4];
#pragma unroll
        for (int i = 0; i < 4; ++i)
            inv[i] = 1.f / fmaxf(sqrtf(ss[i]), 1e-12f);
#pragma unroll
        for (int nt = 0; nt < 4; ++nt)
#pragma unroll
            for (int i = 0; i < 4; ++i)
                Xb[(size_t)(node0 + g * 4 + i) * D + nt * 16 + cl] = f2bf(acc[nt][i] * inv[i]);
    }
}

// ---------------- gather: Agg[n] = sum_{edges dst==n} Xb[src] ----------------
// eighth-wave per edge: 8 lanes x 16B (uint4) cover one 64xbf16 row; 8 edges/iter
__global__ __launch_bounds__(256) void k_gather(const int* __restrict__ nstart,
    const int* __restrict__ nend, const int* __restrict__ srcs,
    const unsigned short* __restrict__ Xb, unsigned short* __restrict__ Ab, int N)
{
    int lane = threadIdx.x & 63, w = threadIdx.x >> 6;
    int node = blockIdx.x * 4 + w;
    if (node >= N) return;
    int start = nstart[node];
    int end = nend[node];
    int g = lane >> 3;          // 8 groups of 8 lanes, one edge each
    int li = lane & 7;          // li covers cols [li*8, li*8+8)
    float acc[8] = {0.f, 0.f, 0.f, 0.f, 0.f, 0.f, 0.f, 0.f};
    for (int base = start; base < end; base += 64) {
        int m = end - base; if (m > 64) m = 64;
        int sid = (base + lane < end) ? srcs[base + lane] : 0;
        int iters = (m + 7) >> 3;
        for (int j = 0; j < iters; ++j) {
            int idx = (j << 3) | g;
            int s = __shfl(sid, idx);
            if (idx < m) {
                uint4 u = *(const uint4*)(Xb + (size_t)s * D + li * 8);
                acc[0] += bf2f((unsigned short)(u.x & 0xFFFFu));
                acc[1] += bf2f((unsigned short)(u.x >> 16));
                acc[2] += bf2f((unsigned short)(u.y & 0xFFFFu));
                acc[3] += bf2f((unsigned short)(u.y >> 16));
                acc[4] += bf2f((unsigned short)(u.z & 0xFFFFu));
                acc[5] += bf2f((unsigned short)(u.z >> 16));
                acc[6] += bf2f((unsigned short)(u.w & 0xFFFFu));
                acc[7] += bf2f((unsigned short)(u.w >> 16));
            }
        }
    }
#pragma unroll
    for (int d = 32; d >= 8; d >>= 1)
#pragma unroll
        for (int i = 0; i < 8; ++i)
            acc[i] += __shfl_xor(acc[i], d);
    if (g == 0) {
        uint4 o;
        o.x = (unsigned)f2bf(acc[0]) | ((unsigned)f2bf(acc[1]) << 16);
        o.y = (unsigned)f2bf(acc[2]) | ((unsigned)f2bf(acc[3]) << 16);
        o.z = (unsigned)f2bf(acc[4]) | ((unsigned)f2bf(acc[5]) << 16);
        o.w = (unsigned)f2bf(acc[6]) | ((unsigned)f2bf(acc[7]) << 16);
        *(uint4*)(Ab + (size_t)node * D + li * 8) = o;
    }
}

// ---------------- fused combine (MFMA), weights staged in LDS:
// O = leaky( leaky(Agg@Wc)@Wg + bg + leaky(X@Wl + bl) + ID ) ----------------
// Wct/Wlt/Wgt: bf16 col-major [64][64] in global; re-strided to [64][WS] in LDS
__global__ __launch_bounds__(256) void k_combine(
    const unsigned short* Xb, const unsigned short* __restrict__ Ab,
    const unsigned short* __restrict__ Wct,
    const unsigned short* __restrict__ Wlt, const float* __restrict__ bl,
    const unsigned short* __restrict__ Wgt, const float* __restrict__ bg,
    const float* __restrict__ ID,
    unsigned short* Ob, float* Of, int N)
{
    __shared__ unsigned short Wc_s[64 * WS], Wl_s[64 * WS], Wg_s[64 * WS];
    __shared__ unsigned short tl[4][16][72];
    int lane = threadIdx.x & 63, w = threadIdx.x >> 6;
    int cl = lane & 15, g = lane >> 4;
    int ntiles = (N + 63) / 64;

    // cooperative weight stage: 512 uint4 per matrix (2 iters/thread)
    for (int i = threadIdx.x; i < 512; i += 256) {
        int r = i >> 3, c8 = (i & 7) << 3;
        *(uint4*)(Wc_s + r * WS + c8) = *(const uint4*)(Wct + r * 64 + c8);
        *(uint4*)(Wl_s + r * WS + c8) = *(const uint4*)(Wlt + r * 64 + c8);
        *(uint4*)(Wg_s + r * WS + c8) = *(const uint4*)(Wgt + r * 64 + c8);
    }
    float blv[4], bgv[4];
#pragma unroll
    for (int nt = 0; nt < 4; ++nt) {
        blv[nt] = bl[nt * 16 + cl];
        bgv[nt] = bg[nt * 16 + cl];
    }
    __syncthreads();

    for (int tb = blockIdx.x; tb < ntiles; tb += gridDim.x) {
        int node0 = tb * 64 + w * 16;
        bool active = node0 < N;
        f32x4 accL[4], accG[4];
        if (active) {
            const bf16x8* xr = (const bf16x8*)(Xb + (size_t)(node0 + cl) * D + g * 8);
            const bf16x8* ar = (const bf16x8*)(Ab + (size_t)(node0 + cl) * D + g * 8);
            bf16x8 xf0 = xr[0], xf1 = xr[4];
            bf16x8 af0 = ar[0], af1 = ar[4];
            f32x4 accC[4];
#pragma unroll
            for (int nt = 0; nt < 4; ++nt) {
                int wo = (nt * 16 + cl) * WS + g * 8;
                f32x4 z = (f32x4){0.f, 0.f, 0.f, 0.f};
                accL[nt] = __builtin_amdgcn_mfma_f32_16x16x32_bf16(
                    *(const bf16x8*)(Wl_s + wo + 32), // ks=1
                    xf1, (f32x4){0,0,0,0}, 0, 0, 0);
                // note: mfma(A,B,C): A = x-fragment, B = weight; keep orig order:
                accL[nt] = __builtin_amdgcn_mfma_f32_16x16x32_bf16(xf1,
                            *(const bf16x8*)(Wl_s + wo + 32),
                            __builtin_amdgcn_mfma_f32_16x16x32_bf16(xf0,
                                *(const bf16x8*)(Wl_s + wo), z, 0, 0, 0), 0, 0, 0);
                accC[nt] = __builtin_amdgcn_mfma_f32_16x16x32_bf16(af1,
                            *(const bf16x8*)(Wc_s + wo + 32),
                            __builtin_amdgcn_mfma_f32_16x16x32_bf16(af0,
                                *(const bf16x8*)(Wc_s + wo), z, 0, 0, 0), 0, 0, 0);
            }
#pragma unroll
            for (int nt = 0; nt < 4; ++nt)
#pragma unroll
                for (int i = 0; i < 4; ++i)
                    tl[w][g * 4 + i][nt * 16 + cl] = f2bf(leaky(accC[nt][i]));
        }
        __syncthreads();
        if (active) {
            const bf16x8* tr = (const bf16x8*)&tl[w][cl][g * 8];
            bf16x8 tf0 = tr[0], tf1 = tr[4];
#pragma unroll
            for (int nt = 0; nt < 4; ++nt) {
                int wo = (nt * 16 + cl) * WS + g * 8;
                f32x4 z = (f32x4){0.f, 0.f, 0.f, 0.f};
                accG[nt] = __builtin_amdgcn_mfma_f32_16x16x32_bf16(tf1,
                            *(const bf16x8*)(Wg_s + wo + 32),
                            __builtin_amdgcn_mfma_f32_16x16x32_bf16(tf0,
                                *(const bf16x8*)(Wg_s + wo), z, 0, 0, 0), 0, 0, 0);
            }
#pragma unroll
            for (int nt = 0; nt < 4; ++nt) {
                int col = nt * 16 + cl;
#pragma unroll
                for (int i = 0; i < 4; ++i) {
                    size_t row = (size_t)(node0 + g * 4 + i);
                    float xh = leaky(accL[nt][i] + blv[nt]) + ID[row * D + col];
                    float o = leaky(accG[nt][i] + bgv[nt] + xh);
                    if (Ob) Ob[row * D + col] = f2bf(o);
                    else    Of[row * D + col] = o;
                }
            }
        }
        __syncthreads();
    }
}

extern "C" void kernel_launch(void* const* d_in, const int* in_sizes, int n_in,
                              void* d_out, int out_size, void* d_ws, size_t ws_size,
                              hipStream_t stream)
{
    const float* features = (const float*)d_in[0];
    const float* id_emb   = (const float*)d_in[1];
    const int*   eidx     = (const int*)d_in[2];
    const float* W_mlp    = (const float*)d_in[3];
    const float* b_mlp    = (const float*)d_in[4];
    const float* Wc1 = (const float*)d_in[5];
    const float* Wl1 = (const float*)d_in[6];
    const float* bl1 = (const float*)d_in[7];
    const float* Wg1 = (const float*)d_in[8];
    const float* bg1 = (const float*)d_in[9];
    const float* Wc2 = (const float*)d_in[10];
    const float* Wl2 = (const float*)d_in[11];
    const float* bl2 = (const float*)d_in[12];
    const float* Wg2 = (const float*)d_in[13];
    const float* bg2 = (const float*)d_in[14];

    int N = in_sizes[0] / D_FEAT;
    int E = in_sizes[2] / 2;
    const int* esrc = eidx;
    const int* edst = eidx + E;
    int nbk = (N + BW - 1) >> BSH;               // 782 for N=100000

    unsigned short* Xb = (unsigned short*)d_ws;  // [N][64] bf16
    unsigned short* Ab = Xb + (size_t)N * D;     // [N][64] bf16
    int* srcs   = (int*)(Ab + (size_t)N * D);    // [nbk*CAP] bucket-strided
    int* nstart = srcs + (size_t)nbk * CAP;      // [N]
    int* nend   = nstart + N;                    // [N]
    int* gcur   = nend + N;                      // [1024]
    unsigned short* wt = (unsigned short*)(gcur + 1024);  // 8192 + 6*4096 bf16
    unsigned short* Wmt  = wt;
    unsigned short* Wct1 = wt + 8192;
    unsigned short* Wlt1 = Wct1 + 4096;
    unsigned short* Wgt1 = Wlt1 + 4096;
    unsigned short* Wct2 = Wgt1 + 4096;
    unsigned short* Wlt2 = Wct2 + 4096;
    unsigned short* Wgt2 = Wlt2 + 4096;

    // pairs scratch lives in d_out (25.6 MB >= nbk*CAP*4 = 8.0 MB); fully dead
    // before the final combine writes d_out.
    unsigned* pairs = (unsigned*)d_out;

    dim3 blk(256);
    int ntiles = (N + 63) / 64;
    int egrid = (E + 4095) / 4096;
    int cgrid = 782;                             // ~3 blocks/CU, 2 tiles each

    P7 p7;
    p7.w[0] = W_mlp; p7.w[1] = Wc1; p7.w[2] = Wl1; p7.w[3] = Wg1;
    p7.w[4] = Wc2; p7.w[5] = Wl2; p7.w[6] = Wg2;

    // weight transpose + gcur init (one dispatch)
    k_prep<<<8, blk, 0, stream>>>(p7, wt, gcur, nbk);

    // bucket CSR build (shared by both layers)
    k_part<<<egrid, blk, 0, stream>>>(esrc, edst, gcur, pairs, E);
    k_sort<<<nbk, blk, 0, stream>>>(pairs, gcur, nstart, nend, srcs, N);

    k_mlp<<<512, blk, 0, stream>>>(features, Wmt, b_mlp, Xb, N);

    // layer 1  (combine writes x1 bf16 in-place over Xb)
    k_gather <<<(N + 3) / 4, blk, 0, stream>>>(nstart, nend, srcs, Xb, Ab, N);
    k_combine<<<cgrid, blk, 0, stream>>>(Xb, Ab, Wct1, Wlt1, bl1, Wgt1, bg1, id_emb,
                                         Xb, (float*)nullptr, N);

    // layer 2
    k_gather <<<(N + 3) / 4, blk, 0, stream>>>(nstart, nend, srcs, Xb, Ab, N);
    k_combine<<<cgrid, blk, 0, stream>>>(Xb, Ab, Wct2, Wlt2, bl2, Wgt2, bg2, id_emb,
                                         (unsigned short*)nullptr, (float*)d_out, N);
}

// Round 11
// 176.325 us; speedup vs baseline: 1.2931x; 1.0104x over previous
//
#include <hip/hip_runtime.h>
#include <cstdint>
#include <cstddef>

#define D 64
#define D_FEAT 128
#define SLOPE 0.01f
#define BSH 7                 // bucket = dst >> 7  (128 nodes per bucket)
#define BW 128
#define CAP 2560              // per-bucket slot capacity (mean 2046, +11 sigma)
#define WS 72                 // LDS weight row stride (bf16): 144B, 16B-aligned, 2-way banks

typedef __attribute__((ext_vector_type(8))) short bf16x8;
typedef __attribute__((ext_vector_type(4))) float f32x4;
typedef __attribute__((ext_vector_type(2))) float f32x2;

struct P7 { const float* w[7]; };

__device__ __forceinline__ float leaky(float v) { return v >= 0.f ? v : SLOPE * v; }

__device__ __forceinline__ unsigned short f2bf(float f) {
    union { float f; unsigned u; } v; v.f = f;
    unsigned r = v.u + 0x7FFF + ((v.u >> 16) & 1);   // RNE
    return (unsigned short)(r >> 16);
}
__device__ __forceinline__ float bf2f(unsigned short b) {
    union { unsigned u; float f; } v; v.u = ((unsigned)b) << 16;
    return v.f;
}

// ---------------- prep: weights fp32 row-major -> bf16 col-major; + gcur init --
// blocks 0..6 = matrices (0: K=128, 1..6: K=64); block 7 inits gcur.
__global__ __launch_bounds__(256) void k_prep(P7 p, unsigned short* __restrict__ out,
    int* __restrict__ gcur, int nbk)
{
    int m = blockIdx.x;
    if (m == 7) {
        for (int i = threadIdx.x; i < nbk; i += 256) gcur[i] = i * CAP;
        return;
    }
    int K = (m == 0) ? 128 : 64;
    const float* W = p.w[m];
    unsigned short* o = out + ((m == 0) ? 0 : 8192 + (m - 1) * 4096);
    int total = K * 64;
    for (int i = threadIdx.x; i < total; i += 256) {
        int col = i / K, k = i - col * K;
        o[i] = f2bf(W[k * 64 + col]);     // o[col*K + k]
    }
}

// ---------------- partition edges into strided buckets (single histogram pass) --
__global__ __launch_bounds__(256) void k_part(const int* __restrict__ esrc,
    const int* __restrict__ edst, int* __restrict__ gcur,
    unsigned* __restrict__ pairs, int E)
{
    __shared__ int lcnt[1024];
    __shared__ int lbase[1024];
    int base = blockIdx.x * 4096;
    for (int i = threadIdx.x; i < 1024; i += 256) lcnt[i] = 0;
    __syncthreads();
    int dv[16], rv[16];
#pragma unroll
    for (int i = 0; i < 16; ++i) {
        int e = base + i * 256 + threadIdx.x;
        if (e < E) {
            dv[i] = edst[e];
            rv[i] = atomicAdd(&lcnt[dv[i] >> BSH], 1);
        } else dv[i] = -1;
    }
    __syncthreads();
    for (int i = threadIdx.x; i < 1024; i += 256) {
        int c = lcnt[i];
        lbase[i] = c ? atomicAdd(&gcur[i], c) : 0;
    }
    __syncthreads();
#pragma unroll
    for (int i = 0; i < 16; ++i) {
        if (dv[i] >= 0) {
            int e = base + i * 256 + threadIdx.x;
            unsigned pk = ((unsigned)(dv[i] & (BW - 1)) << 25) | (unsigned)esrc[e];
            pairs[lbase[dv[i] >> BSH] + rv[i]] = pk;
        }
    }
}

// ---------------- per-bucket counting sort -> per-node ranges (coalesced) ------
__global__ __launch_bounds__(256) void k_sort(const unsigned* __restrict__ pairs,
    const int* __restrict__ gcur, int* __restrict__ nstart, int* __restrict__ nend,
    int* __restrict__ srcs, int N)
{
    __shared__ int lh[BW];
    __shared__ int cur[BW];
    __shared__ unsigned buf[CAP];
    int b = blockIdx.x;
    int node0 = b << BSH;
    int s0 = b * CAP;
    int cnt = gcur[b] - s0;
    if (threadIdx.x < BW) lh[threadIdx.x] = 0;
    __syncthreads();
    for (int i = threadIdx.x; i < cnt; i += 256)
        atomicAdd(&lh[pairs[s0 + i] >> 25], 1);
    __syncthreads();
    if (threadIdx.x < 64) {   // wave 0: exclusive scan of 128 counts, 2/lane
        int a = lh[2 * threadIdx.x], c = lh[2 * threadIdx.x + 1];
        int s = a + c, inc = s;
#pragma unroll
        for (int d = 1; d < 64; d <<= 1) {
            int u = __shfl_up(inc, d);
            if ((int)threadIdx.x >= d) inc += u;
        }
        int ex = inc - s;
        cur[2 * threadIdx.x] = ex;
        cur[2 * threadIdx.x + 1] = ex + a;
    }
    __syncthreads();
    if (threadIdx.x < BW) {
        int node = node0 + threadIdx.x;
        if (node < N) {
            nstart[node] = s0 + cur[threadIdx.x];
            nend[node]   = s0 + cur[threadIdx.x] + lh[threadIdx.x];
        }
    }
    __syncthreads();
    for (int i = threadIdx.x; i < cnt; i += 256) {
        unsigned p = pairs[s0 + i];
        int r = atomicAdd(&cur[p >> 25], 1);
        buf[r] = p & 0x1FFFFFFu;
    }
    __syncthreads();
    for (int i = threadIdx.x; i < cnt; i += 256)
        srcs[s0 + i] = (int)buf[i];
}

// ---------------- MLP + L2 norm (MFMA), fp32 in -> bf16 + fp8 out ----------------
// Wt: bf16 col-major [64][128]
__global__ __launch_bounds__(256) void k_mlp(const float* __restrict__ F,
    const unsigned short* __restrict__ Wt, const float* __restrict__ bm,
    unsigned short* __restrict__ Xb, unsigned char* __restrict__ Xf8, int N)
{
    int lane = threadIdx.x & 63, w = threadIdx.x >> 6;
    int cl = lane & 15, g = lane >> 4;
    int ntiles = (N + 63) / 64;

    bf16x8 Wmf[4][4];
#pragma unroll
    for (int ks = 0; ks < 4; ++ks)
#pragma unroll
        for (int nt = 0; nt < 4; ++nt)
            Wmf[ks][nt] = *(const bf16x8*)(Wt + (nt * 16 + cl) * 128 + ks * 32 + g * 8);
    float bmv[4];
#pragma unroll
    for (int nt = 0; nt < 4; ++nt) bmv[nt] = bm[nt * 16 + cl];

    for (int tb = blockIdx.x; tb < ntiles; tb += gridDim.x) {
        int node0 = tb * 64 + w * 16;
        if (node0 >= N) continue;
        f32x4 acc[4];
#pragma unroll
        for (int nt = 0; nt < 4; ++nt) acc[nt] = (f32x4){0.f, 0.f, 0.f, 0.f};
#pragma unroll
        for (int ks = 0; ks < 4; ++ks) {
            const float4* fp = (const float4*)(F + (size_t)(node0 + cl) * D_FEAT + ks * 32 + g * 8);
            float4 a = fp[0], b = fp[1];
            bf16x8 af;
            af[0] = (short)f2bf(a.x); af[1] = (short)f2bf(a.y);
            af[2] = (short)f2bf(a.z); af[3] = (short)f2bf(a.w);
            af[4] = (short)f2bf(b.x); af[5] = (short)f2bf(b.y);
            af[6] = (short)f2bf(b.z); af[7] = (short)f2bf(b.w);
#pragma unroll
            for (int nt = 0; nt < 4; ++nt)
                acc[nt] = __builtin_amdgcn_mfma_f32_16x16x32_bf16(af, Wmf[ks][nt], acc[nt], 0, 0, 0);
        }
        float ss[4] = {0.f, 0.f, 0.f, 0.f};
#pragma unroll
        for (int nt = 0; nt < 4; ++nt)
#pragma unroll
            for (int i = 0; i < 4; ++i) {
                float v = acc[nt][i] + bmv[nt];
                acc[nt][i] = v;
                ss[i] += v * v;
            }
#pragma unroll
        for (int off = 8; off >= 1; off >>= 1)
#pragma unroll
            for (int i = 0; i < 4; ++i)
                ss[i] += __shfl_xor(ss[i], off);
        float inv[4];
#pragma unroll
        for (int i = 0; i < 4; ++i)
            inv[i] = 1.f / fmaxf(sqrtf(ss[i]), 1e-12f);
#pragma unroll
        for (int nt = 0; nt < 4; ++nt)
#pragma unroll
            for (int i = 0; i < 4; ++i) {
                float v = acc[nt][i] * inv[i];
                size_t row = (size_t)(node0 + g * 4 + i);
                Xb[row * D + nt * 16 + cl] = f2bf(v);
                int p8 = __builtin_amdgcn_cvt_pk_fp8_f32(v, v, 0, false);
                Xf8[row * D + nt * 16 + cl] = (unsigned char)(p8 & 0xFF);
            }
    }
}

// ---------------- gather (fp8 rows): Agg[n] = sum Xf8[src]; bf16 out ----------
// eighth-wave per edge: 8 lanes x 8B (uint2 = 8 fp8) cover a 64-col row
__global__ __launch_bounds__(256) void k_gather8(const int* __restrict__ nstart,
    const int* __restrict__ nend, const int* __restrict__ srcs,
    const unsigned char* __restrict__ Xf8, unsigned short* __restrict__ Ab, int N)
{
    int lane = threadIdx.x & 63, w = threadIdx.x >> 6;
    int node = blockIdx.x * 4 + w;
    if (node >= N) return;
    int start = nstart[node];
    int end = nend[node];
    int g = lane >> 3;          // 8 groups of 8 lanes, one edge each
    int li = lane & 7;          // li covers cols [li*8, li*8+8)
    f32x2 acc[4];
#pragma unroll
    for (int i = 0; i < 4; ++i) acc[i] = (f32x2){0.f, 0.f};
    for (int base = start; base < end; base += 64) {
        int m = end - base; if (m > 64) m = 64;
        int sid = (base + lane < end) ? srcs[base + lane] : 0;
        int iters = (m + 7) >> 3;
        for (int j = 0; j < iters; ++j) {
            int idx = (j << 3) | g;
            int s = __shfl(sid, idx);
            if (idx < m) {
                uint2 u = *(const uint2*)(Xf8 + (size_t)s * D + li * 8);
                acc[0] += __builtin_amdgcn_cvt_pk_f32_fp8(u.x, false);
                acc[1] += __builtin_amdgcn_cvt_pk_f32_fp8(u.x, true);
                acc[2] += __builtin_amdgcn_cvt_pk_f32_fp8(u.y, false);
                acc[3] += __builtin_amdgcn_cvt_pk_f32_fp8(u.y, true);
            }
        }
    }
#pragma unroll
    for (int d = 32; d >= 8; d >>= 1)
#pragma unroll
        for (int i = 0; i < 4; ++i) {
            acc[i].x += __shfl_xor(acc[i].x, d);
            acc[i].y += __shfl_xor(acc[i].y, d);
        }
    if (g == 0) {
        uint4 o;
        o.x = (unsigned)f2bf(acc[0].x) | ((unsigned)f2bf(acc[0].y) << 16);
        o.y = (unsigned)f2bf(acc[1].x) | ((unsigned)f2bf(acc[1].y) << 16);
        o.z = (unsigned)f2bf(acc[2].x) | ((unsigned)f2bf(acc[2].y) << 16);
        o.w = (unsigned)f2bf(acc[3].x) | ((unsigned)f2bf(acc[3].y) << 16);
        *(uint4*)(Ab + (size_t)node * D + li * 8) = o;
    }
}

// ---------------- gather (bf16 rows): layer 2 ----------------
__global__ __launch_bounds__(256) void k_gather(const int* __restrict__ nstart,
    const int* __restrict__ nend, const int* __restrict__ srcs,
    const unsigned short* __restrict__ Xb, unsigned short* __restrict__ Ab, int N)
{
    int lane = threadIdx.x & 63, w = threadIdx.x >> 6;
    int node = blockIdx.x * 4 + w;
    if (node >= N) return;
    int start = nstart[node];
    int end = nend[node];
    int g = lane >> 3;          // 8 groups of 8 lanes, one edge each
    int li = lane & 7;          // li covers cols [li*8, li*8+8)
    float acc[8] = {0.f, 0.f, 0.f, 0.f, 0.f, 0.f, 0.f, 0.f};
    for (int base = start; base < end; base += 64) {
        int m = end - base; if (m > 64) m = 64;
        int sid = (base + lane < end) ? srcs[base + lane] : 0;
        int iters = (m + 7) >> 3;
        for (int j = 0; j < iters; ++j) {
            int idx = (j << 3) | g;
            int s = __shfl(sid, idx);
            if (idx < m) {
                uint4 u = *(const uint4*)(Xb + (size_t)s * D + li * 8);
                acc[0] += bf2f((unsigned short)(u.x & 0xFFFFu));
                acc[1] += bf2f((unsigned short)(u.x >> 16));
                acc[2] += bf2f((unsigned short)(u.y & 0xFFFFu));
                acc[3] += bf2f((unsigned short)(u.y >> 16));
                acc[4] += bf2f((unsigned short)(u.z & 0xFFFFu));
                acc[5] += bf2f((unsigned short)(u.z >> 16));
                acc[6] += bf2f((unsigned short)(u.w & 0xFFFFu));
                acc[7] += bf2f((unsigned short)(u.w >> 16));
            }
        }
    }
#pragma unroll
    for (int d = 32; d >= 8; d >>= 1)
#pragma unroll
        for (int i = 0; i < 8; ++i)
            acc[i] += __shfl_xor(acc[i], d);
    if (g == 0) {
        uint4 o;
        o.x = (unsigned)f2bf(acc[0]) | ((unsigned)f2bf(acc[1]) << 16);
        o.y = (unsigned)f2bf(acc[2]) | ((unsigned)f2bf(acc[3]) << 16);
        o.z = (unsigned)f2bf(acc[4]) | ((unsigned)f2bf(acc[5]) << 16);
        o.w = (unsigned)f2bf(acc[6]) | ((unsigned)f2bf(acc[7]) << 16);
        *(uint4*)(Ab + (size_t)node * D + li * 8) = o;
    }
}

// ---------------- fused combine (MFMA), weights staged in LDS ----------------
__global__ __launch_bounds__(256) void k_combine(
    const unsigned short* Xb, const unsigned short* __restrict__ Ab,
    const unsigned short* __restrict__ Wct,
    const unsigned short* __restrict__ Wlt, const float* __restrict__ bl,
    const unsigned short* __restrict__ Wgt, const float* __restrict__ bg,
    const float* __restrict__ ID,
    unsigned short* Ob, float* Of, int N)
{
    __shared__ unsigned short Wc_s[64 * WS], Wl_s[64 * WS], Wg_s[64 * WS];
    __shared__ unsigned short tl[4][16][72];
    int lane = threadIdx.x & 63, w = threadIdx.x >> 6;
    int cl = lane & 15, g = lane >> 4;
    int ntiles = (N + 63) / 64;

    for (int i = threadIdx.x; i < 512; i += 256) {
        int r = i >> 3, c8 = (i & 7) << 3;
        *(uint4*)(Wc_s + r * WS + c8) = *(const uint4*)(Wct + r * 64 + c8);
        *(uint4*)(Wl_s + r * WS + c8) = *(const uint4*)(Wlt + r * 64 + c8);
        *(uint4*)(Wg_s + r * WS + c8) = *(const uint4*)(Wgt + r * 64 + c8);
    }
    float blv[4], bgv[4];
#pragma unroll
    for (int nt = 0; nt < 4; ++nt) {
        blv[nt] = bl[nt * 16 + cl];
        bgv[nt] = bg[nt * 16 + cl];
    }
    __syncthreads();

    for (int tb = blockIdx.x; tb < ntiles; tb += gridDim.x) {
        int node0 = tb * 64 + w * 16;
        bool active = node0 < N;
        f32x4 accL[4], accG[4];
        if (active) {
            const bf16x8* xr = (const bf16x8*)(Xb + (size_t)(node0 + cl) * D + g * 8);
            const bf16x8* ar = (const bf16x8*)(Ab + (size_t)(node0 + cl) * D + g * 8);
            bf16x8 xf0 = xr[0], xf1 = xr[4];
            bf16x8 af0 = ar[0], af1 = ar[4];
            f32x4 accC[4];
#pragma unroll
            for (int nt = 0; nt < 4; ++nt) {
                int wo = (nt * 16 + cl) * WS + g * 8;
                f32x4 z = (f32x4){0.f, 0.f, 0.f, 0.f};
                accL[nt] = __builtin_amdgcn_mfma_f32_16x16x32_bf16(xf1,
                            *(const bf16x8*)(Wl_s + wo + 32),
                            __builtin_amdgcn_mfma_f32_16x16x32_bf16(xf0,
                                *(const bf16x8*)(Wl_s + wo), z, 0, 0, 0), 0, 0, 0);
                accC[nt] = __builtin_amdgcn_mfma_f32_16x16x32_bf16(af1,
                            *(const bf16x8*)(Wc_s + wo + 32),
                            __builtin_amdgcn_mfma_f32_16x16x32_bf16(af0,
                                *(const bf16x8*)(Wc_s + wo), z, 0, 0, 0), 0, 0, 0);
            }
#pragma unroll
            for (int nt = 0; nt < 4; ++nt)
#pragma unroll
                for (int i = 0; i < 4; ++i)
                    tl[w][g * 4 + i][nt * 16 + cl] = f2bf(leaky(accC[nt][i]));
        }
        __syncthreads();
        if (active) {
            const bf16x8* tr = (const bf16x8*)&tl[w][cl][g * 8];
            bf16x8 tf0 = tr[0], tf1 = tr[4];
#pragma unroll
            for (int nt = 0; nt < 4; ++nt) {
                int wo = (nt * 16 + cl) * WS + g * 8;
                f32x4 z = (f32x4){0.f, 0.f, 0.f, 0.f};
                accG[nt] = __builtin_amdgcn_mfma_f32_16x16x32_bf16(tf1,
                            *(const bf16x8*)(Wg_s + wo + 32),
                            __builtin_amdgcn_mfma_f32_16x16x32_bf16(tf0,
                                *(const bf16x8*)(Wg_s + wo), z, 0, 0, 0), 0, 0, 0);
            }
#pragma unroll
            for (int nt = 0; nt < 4; ++nt) {
                int col = nt * 16 + cl;
#pragma unroll
                for (int i = 0; i < 4; ++i) {
                    size_t row = (size_t)(node0 + g * 4 + i);
                    float xh = leaky(accL[nt][i] + blv[nt]) + ID[row * D + col];
                    float o = leaky(accG[nt][i] + bgv[nt] + xh);
                    if (Ob) Ob[row * D + col] = f2bf(o);
                    else    Of[row * D + col] = o;
                }
            }
        }
        __syncthreads();
    }
}

extern "C" void kernel_launch(void* const* d_in, const int* in_sizes, int n_in,
                              void* d_out, int out_size, void* d_ws, size_t ws_size,
                              hipStream_t stream)
{
    const float* features = (const float*)d_in[0];
    const float* id_emb   = (const float*)d_in[1];
    const int*   eidx     = (const int*)d_in[2];
    const float* W_mlp    = (const float*)d_in[3];
    const float* b_mlp    = (const float*)d_in[4];
    const float* Wc1 = (const float*)d_in[5];
    const float* Wl1 = (const float*)d_in[6];
    const float* bl1 = (const float*)d_in[7];
    const float* Wg1 = (const float*)d_in[8];
    const float* bg1 = (const float*)d_in[9];
    const float* Wc2 = (const float*)d_in[10];
    const float* Wl2 = (const float*)d_in[11];
    const float* bl2 = (const float*)d_in[12];
    const float* Wg2 = (const float*)d_in[13];
    const float* bg2 = (const float*)d_in[14];

    int N = in_sizes[0] / D_FEAT;
    int E = in_sizes[2] / 2;
    const int* esrc = eidx;
    const int* edst = eidx + E;
    int nbk = (N + BW - 1) >> BSH;               // 782 for N=100000

    unsigned short* Xb = (unsigned short*)d_ws;  // [N][64] bf16
    unsigned short* Ab = Xb + (size_t)N * D;     // [N][64] bf16
    int* srcs   = (int*)(Ab + (size_t)N * D);    // [nbk*CAP] bucket-strided
    int* nstart = srcs + (size_t)nbk * CAP;      // [N]
    int* nend   = nstart + N;                    // [N]
    int* gcur   = nend + N;                      // [1024]
    unsigned short* wt = (unsigned short*)(gcur + 1024);  // 8192 + 6*4096 bf16
    unsigned short* Wmt  = wt;
    unsigned short* Wct1 = wt + 8192;
    unsigned short* Wlt1 = Wct1 + 4096;
    unsigned short* Wgt1 = Wlt1 + 4096;
    unsigned short* Wct2 = Wgt1 + 4096;
    unsigned short* Wlt2 = Wct2 + 4096;
    unsigned short* Wgt2 = Wlt2 + 4096;
    unsigned char* Xf8 = (unsigned char*)(Wgt2 + 4096);   // [N][64] fp8

    // pairs scratch lives in d_out (25.6 MB >= nbk*CAP*4 = 8.0 MB); fully dead
    // before the final combine writes d_out.
    unsigned* pairs = (unsigned*)d_out;

    dim3 blk(256);
    int egrid = (E + 4095) / 4096;
    int cgrid = 782;                             // ~3 blocks/CU, 2 tiles each

    P7 p7;
    p7.w[0] = W_mlp; p7.w[1] = Wc1; p7.w[2] = Wl1; p7.w[3] = Wg1;
    p7.w[4] = Wc2; p7.w[5] = Wl2; p7.w[6] = Wg2;

    // weight transpose + gcur init (one dispatch)
    k_prep<<<8, blk, 0, stream>>>(p7, wt, gcur, nbk);

    // bucket CSR build (shared by both layers)
    k_part<<<egrid, blk, 0, stream>>>(esrc, edst, gcur, pairs, E);
    k_sort<<<nbk, blk, 0, stream>>>(pairs, gcur, nstart, nend, srcs, N);

    k_mlp<<<512, blk, 0, stream>>>(features, Wmt, b_mlp, Xb, Xf8, N);

    // layer 1: fp8 gather (x small after L2-norm -> negligible fp8 error)
    k_gather8<<<(N + 3) / 4, blk, 0, stream>>>(nstart, nend, srcs, Xf8, Ab, N);
    k_combine<<<cgrid, blk, 0, stream>>>(Xb, Ab, Wct1, Wlt1, bl1, Wgt1, bg1, id_emb,
                                         Xb, (float*)nullptr, N);

    // layer 2: bf16 gather (x1 is id_emb-dominated, fp8 too lossy)
    k_gather<<<(N + 3) / 4, blk, 0, stream>>>(nstart, nend, srcs, Xb, Ab, N);
    k_combine<<<cgrid, blk, 0, stream>>>(Xb, Ab, Wct2, Wlt2, bl2, Wgt2, bg2, id_emb,
                                         (unsigned short*)nullptr, (float*)d_out, N);
}

// Round 12
// 164.346 us; speedup vs baseline: 1.3874x; 1.0729x over previous
//
#include <hip/hip_runtime.h>
#include <cstdint>
#include <cstddef>

#define D 64
#define D_FEAT 128
#define SLOPE 0.01f
#define BSH 7                 // bucket = dst >> 7  (128 nodes per bucket)
#define BW 128
#define CAP 2560              // per-bucket slot capacity (mean 2046, +11 sigma)
#define WS 72                 // LDS weight row stride (bf16): 144B, 16B-aligned, 2-way banks

typedef __attribute__((ext_vector_type(8))) short bf16x8;
typedef __attribute__((ext_vector_type(4))) float f32x4;
typedef __attribute__((ext_vector_type(2))) float f32x2;

struct P7 { const float* w[7]; };

__device__ __forceinline__ float leaky(float v) { return v >= 0.f ? v : SLOPE * v; }

__device__ __forceinline__ unsigned short f2bf(float f) {
    union { float f; unsigned u; } v; v.f = f;
    unsigned r = v.u + 0x7FFF + ((v.u >> 16) & 1);   // RNE
    return (unsigned short)(r >> 16);
}
__device__ __forceinline__ float bf2f(unsigned short b) {
    union { unsigned u; float f; } v; v.u = ((unsigned)b) << 16;
    return v.f;
}
// one-instruction packed f32->2xbf16 (RNE); no builtin on gfx950
__device__ __forceinline__ unsigned pk_bf16(float lo, float hi) {
    unsigned r;
    asm("v_cvt_pk_bf16_f32 %0, %1, %2" : "=v"(r) : "v"(lo), "v"(hi));
    return r;
}

// ---------------- prep: weights fp32 row-major -> bf16 col-major; + gcur init --
__global__ __launch_bounds__(256) void k_prep(P7 p, unsigned short* __restrict__ out,
    int* __restrict__ gcur, int nbk)
{
    int m = blockIdx.x;
    if (m == 7) {
        for (int i = threadIdx.x; i < nbk; i += 256) gcur[i] = i * CAP;
        return;
    }
    int K = (m == 0) ? 128 : 64;
    const float* W = p.w[m];
    unsigned short* o = out + ((m == 0) ? 0 : 8192 + (m - 1) * 4096);
    int total = K * 64;
    for (int i = threadIdx.x; i < total; i += 256) {
        int col = i / K, k = i - col * K;
        o[i] = f2bf(W[k * 64 + col]);     // o[col*K + k]
    }
}

// ---------------- fused: edge partition (blocks 0..nPart-1) || MLP (rest) ------
__global__ __launch_bounds__(256) void k_partmlp(
    const int* __restrict__ esrc, const int* __restrict__ edst,
    int* __restrict__ gcur, unsigned* __restrict__ pairs, int E, int nPart,
    const float* __restrict__ F, const unsigned short* __restrict__ Wt,
    const float* __restrict__ bm,
    unsigned short* __restrict__ Xb, unsigned char* __restrict__ Xf8, int N)
{
    __shared__ int lcnt[1024];
    __shared__ int lbase[1024];
    if ((int)blockIdx.x < nPart) {
        // ---- partition branch (single histogram pass) ----
        int base = blockIdx.x * 4096;
        for (int i = threadIdx.x; i < 1024; i += 256) lcnt[i] = 0;
        __syncthreads();
        int dv[16], rv[16];
#pragma unroll
        for (int i = 0; i < 16; ++i) {
            int e = base + i * 256 + threadIdx.x;
            if (e < E) {
                dv[i] = edst[e];
                rv[i] = atomicAdd(&lcnt[dv[i] >> BSH], 1);
            } else dv[i] = -1;
        }
        __syncthreads();
        for (int i = threadIdx.x; i < 1024; i += 256) {
            int c = lcnt[i];
            lbase[i] = c ? atomicAdd(&gcur[i], c) : 0;
        }
        __syncthreads();
#pragma unroll
        for (int i = 0; i < 16; ++i) {
            if (dv[i] >= 0) {
                int e = base + i * 256 + threadIdx.x;
                unsigned pk = ((unsigned)(dv[i] & (BW - 1)) << 25) | (unsigned)esrc[e];
                pairs[lbase[dv[i] >> BSH] + rv[i]] = pk;
            }
        }
        return;
    }
    // ---- MLP branch: x = L2norm(F@Wm + bm) -> bf16 + fp8 ----
    int lane = threadIdx.x & 63, w = threadIdx.x >> 6;
    int cl = lane & 15, g = lane >> 4;
    int ntiles = (N + 63) / 64;
    int tb0 = blockIdx.x - nPart;
    int step = gridDim.x - nPart;

    bf16x8 Wmf[4][4];
#pragma unroll
    for (int ks = 0; ks < 4; ++ks)
#pragma unroll
        for (int nt = 0; nt < 4; ++nt)
            Wmf[ks][nt] = *(const bf16x8*)(Wt + (nt * 16 + cl) * 128 + ks * 32 + g * 8);
    float bmv[4];
#pragma unroll
    for (int nt = 0; nt < 4; ++nt) bmv[nt] = bm[nt * 16 + cl];

    for (int tb = tb0; tb < ntiles; tb += step) {
        int node0 = tb * 64 + w * 16;
        if (node0 >= N) continue;
        f32x4 acc[4];
#pragma unroll
        for (int nt = 0; nt < 4; ++nt) acc[nt] = (f32x4){0.f, 0.f, 0.f, 0.f};
#pragma unroll
        for (int ks = 0; ks < 4; ++ks) {
            const float4* fp = (const float4*)(F + (size_t)(node0 + cl) * D_FEAT + ks * 32 + g * 8);
            float4 a = fp[0], b = fp[1];
            bf16x8 af;
            af[0] = (short)f2bf(a.x); af[1] = (short)f2bf(a.y);
            af[2] = (short)f2bf(a.z); af[3] = (short)f2bf(a.w);
            af[4] = (short)f2bf(b.x); af[5] = (short)f2bf(b.y);
            af[6] = (short)f2bf(b.z); af[7] = (short)f2bf(b.w);
#pragma unroll
            for (int nt = 0; nt < 4; ++nt)
                acc[nt] = __builtin_amdgcn_mfma_f32_16x16x32_bf16(af, Wmf[ks][nt], acc[nt], 0, 0, 0);
        }
        float ss[4] = {0.f, 0.f, 0.f, 0.f};
#pragma unroll
        for (int nt = 0; nt < 4; ++nt)
#pragma unroll
            for (int i = 0; i < 4; ++i) {
                float v = acc[nt][i] + bmv[nt];
                acc[nt][i] = v;
                ss[i] += v * v;
            }
#pragma unroll
        for (int off = 8; off >= 1; off >>= 1)
#pragma unroll
            for (int i = 0; i < 4; ++i)
                ss[i] += __shfl_xor(ss[i], off);
        float inv[4];
#pragma unroll
        for (int i = 0; i < 4; ++i)
            inv[i] = 1.f / fmaxf(sqrtf(ss[i]), 1e-12f);
#pragma unroll
        for (int nt = 0; nt < 4; ++nt)
#pragma unroll
            for (int i = 0; i < 4; ++i) {
                float v = acc[nt][i] * inv[i];
                size_t row = (size_t)(node0 + g * 4 + i);
                Xb[row * D + nt * 16 + cl] = f2bf(v);
                int p8 = __builtin_amdgcn_cvt_pk_fp8_f32(v, v, 0, false);
                Xf8[row * D + nt * 16 + cl] = (unsigned char)(p8 & 0xFF);
            }
    }
}

// ---------------- per-bucket counting sort -> per-node ranges (coalesced) ------
__global__ __launch_bounds__(256) void k_sort(const unsigned* __restrict__ pairs,
    const int* __restrict__ gcur, int2* __restrict__ rng,
    int* __restrict__ srcs, int N)
{
    __shared__ int lh[BW];
    __shared__ int cur[BW];
    __shared__ unsigned buf[CAP];
    int b = blockIdx.x;
    int node0 = b << BSH;
    int s0 = b * CAP;
    int cnt = gcur[b] - s0;
    if (threadIdx.x < BW) lh[threadIdx.x] = 0;
    __syncthreads();
    for (int i = threadIdx.x; i < cnt; i += 256)
        atomicAdd(&lh[pairs[s0 + i] >> 25], 1);
    __syncthreads();
    if (threadIdx.x < 64) {   // wave 0: exclusive scan of 128 counts, 2/lane
        int a = lh[2 * threadIdx.x], c = lh[2 * threadIdx.x + 1];
        int s = a + c, inc = s;
#pragma unroll
        for (int d = 1; d < 64; d <<= 1) {
            int u = __shfl_up(inc, d);
            if ((int)threadIdx.x >= d) inc += u;
        }
        int ex = inc - s;
        cur[2 * threadIdx.x] = ex;
        cur[2 * threadIdx.x + 1] = ex + a;
    }
    __syncthreads();
    if (threadIdx.x < BW) {
        int node = node0 + threadIdx.x;
        if (node < N)
            rng[node] = make_int2(s0 + cur[threadIdx.x],
                                  s0 + cur[threadIdx.x] + lh[threadIdx.x]);
    }
    __syncthreads();
    for (int i = threadIdx.x; i < cnt; i += 256) {
        unsigned p = pairs[s0 + i];
        int r = atomicAdd(&cur[p >> 25], 1);
        buf[r] = p & 0x1FFFFFFu;
    }
    __syncthreads();
    for (int i = threadIdx.x; i < cnt; i += 256)
        srcs[s0 + i] = (int)buf[i];
}

// ---------------- gather (fp8 rows): Agg[n] = sum Xf8[src]; bf16 out ----------
__global__ __launch_bounds__(256) void k_gather8(const int2* __restrict__ rng,
    const int* __restrict__ srcs,
    const unsigned char* __restrict__ Xf8, unsigned short* __restrict__ Ab, int N)
{
    int lane = threadIdx.x & 63, w = threadIdx.x >> 6;
    int node = blockIdx.x * 4 + w;
    if (node >= N) return;
    int2 r = rng[node];
    int start = r.x, end = r.y;
    int g = lane >> 3;          // 8 groups of 8 lanes, one edge each
    int li = lane & 7;          // li covers cols [li*8, li*8+8)
    f32x2 acc[4];
#pragma unroll
    for (int i = 0; i < 4; ++i) acc[i] = (f32x2){0.f, 0.f};
    for (int base = start; base < end; base += 64) {
        int m = end - base; if (m > 64) m = 64;
        int sid = (base + lane < end) ? srcs[base + lane] : 0;
        int iters = (m + 7) >> 3;
        for (int j = 0; j < iters; ++j) {
            int idx = (j << 3) | g;
            int s = __shfl(sid, idx);
            if (idx < m) {
                uint2 u = *(const uint2*)(Xf8 + (size_t)s * D + li * 8);
                acc[0] += __builtin_amdgcn_cvt_pk_f32_fp8(u.x, false);
                acc[1] += __builtin_amdgcn_cvt_pk_f32_fp8(u.x, true);
                acc[2] += __builtin_amdgcn_cvt_pk_f32_fp8(u.y, false);
                acc[3] += __builtin_amdgcn_cvt_pk_f32_fp8(u.y, true);
            }
        }
    }
#pragma unroll
    for (int d = 32; d >= 8; d >>= 1)
#pragma unroll
        for (int i = 0; i < 4; ++i) {
            acc[i].x += __shfl_xor(acc[i].x, d);
            acc[i].y += __shfl_xor(acc[i].y, d);
        }
    if (g == 0) {
        uint4 o;
        o.x = pk_bf16(acc[0].x, acc[0].y);
        o.y = pk_bf16(acc[1].x, acc[1].y);
        o.z = pk_bf16(acc[2].x, acc[2].y);
        o.w = pk_bf16(acc[3].x, acc[3].y);
        *(uint4*)(Ab + (size_t)node * D + li * 8) = o;
    }
}

// ---------------- gather (bf16 rows): layer 2 ----------------
__global__ __launch_bounds__(256) void k_gather(const int2* __restrict__ rng,
    const int* __restrict__ srcs,
    const unsigned short* __restrict__ Xb, unsigned short* __restrict__ Ab, int N)
{
    int lane = threadIdx.x & 63, w = threadIdx.x >> 6;
    int node = blockIdx.x * 4 + w;
    if (node >= N) return;
    int2 r = rng[node];
    int start = r.x, end = r.y;
    int g = lane >> 3;          // 8 groups of 8 lanes, one edge each
    int li = lane & 7;          // li covers cols [li*8, li*8+8)
    float acc[8] = {0.f, 0.f, 0.f, 0.f, 0.f, 0.f, 0.f, 0.f};
    for (int base = start; base < end; base += 64) {
        int m = end - base; if (m > 64) m = 64;
        int sid = (base + lane < end) ? srcs[base + lane] : 0;
        int iters = (m + 7) >> 3;
        for (int j = 0; j < iters; ++j) {
            int idx = (j << 3) | g;
            int s = __shfl(sid, idx);
            if (idx < m) {
                uint4 u = *(const uint4*)(Xb + (size_t)s * D + li * 8);
                acc[0] += bf2f((unsigned short)(u.x & 0xFFFFu));
                acc[1] += bf2f((unsigned short)(u.x >> 16));
                acc[2] += bf2f((unsigned short)(u.y & 0xFFFFu));
                acc[3] += bf2f((unsigned short)(u.y >> 16));
                acc[4] += bf2f((unsigned short)(u.z & 0xFFFFu));
                acc[5] += bf2f((unsigned short)(u.z >> 16));
                acc[6] += bf2f((unsigned short)(u.w & 0xFFFFu));
                acc[7] += bf2f((unsigned short)(u.w >> 16));
            }
        }
    }
#pragma unroll
    for (int d = 32; d >= 8; d >>= 1)
#pragma unroll
        for (int i = 0; i < 8; ++i)
            acc[i] += __shfl_xor(acc[i], d);
    if (g == 0) {
        uint4 o;
        o.x = pk_bf16(acc[0], acc[1]);
        o.y = pk_bf16(acc[2], acc[3]);
        o.z = pk_bf16(acc[4], acc[5]);
        o.w = pk_bf16(acc[6], acc[7]);
        *(uint4*)(Ab + (size_t)node * D + li * 8) = o;
    }
}

// ---------------- fused combine (MFMA), weights staged in LDS ----------------
__global__ __launch_bounds__(256) void k_combine(
    const unsigned short* Xb, const unsigned short* __restrict__ Ab,
    const unsigned short* __restrict__ Wct,
    const unsigned short* __restrict__ Wlt, const float* __restrict__ bl,
    const unsigned short* __restrict__ Wgt, const float* __restrict__ bg,
    const float* __restrict__ ID,
    unsigned short* Ob, float* Of, int N)
{
    __shared__ unsigned short Wc_s[64 * WS], Wl_s[64 * WS], Wg_s[64 * WS];
    __shared__ unsigned short tl[4][16][72];
    int lane = threadIdx.x & 63, w = threadIdx.x >> 6;
    int cl = lane & 15, g = lane >> 4;
    int ntiles = (N + 63) / 64;

    for (int i = threadIdx.x; i < 512; i += 256) {
        int r = i >> 3, c8 = (i & 7) << 3;
        *(uint4*)(Wc_s + r * WS + c8) = *(const uint4*)(Wct + r * 64 + c8);
        *(uint4*)(Wl_s + r * WS + c8) = *(const uint4*)(Wlt + r * 64 + c8);
        *(uint4*)(Wg_s + r * WS + c8) = *(const uint4*)(Wgt + r * 64 + c8);
    }
    float blv[4], bgv[4];
#pragma unroll
    for (int nt = 0; nt < 4; ++nt) {
        blv[nt] = bl[nt * 16 + cl];
        bgv[nt] = bg[nt * 16 + cl];
    }
    __syncthreads();

    for (int tb = blockIdx.x; tb < ntiles; tb += gridDim.x) {
        int node0 = tb * 64 + w * 16;
        bool active = node0 < N;
        f32x4 accL[4], accG[4];
        if (active) {
            const bf16x8* xr = (const bf16x8*)(Xb + (size_t)(node0 + cl) * D + g * 8);
            const bf16x8* ar = (const bf16x8*)(Ab + (size_t)(node0 + cl) * D + g * 8);
            bf16x8 xf0 = xr[0], xf1 = xr[4];
            bf16x8 af0 = ar[0], af1 = ar[4];
            f32x4 accC[4];
#pragma unroll
            for (int nt = 0; nt < 4; ++nt) {
                int wo = (nt * 16 + cl) * WS + g * 8;
                f32x4 z = (f32x4){0.f, 0.f, 0.f, 0.f};
                accL[nt] = __builtin_amdgcn_mfma_f32_16x16x32_bf16(xf1,
                            *(const bf16x8*)(Wl_s + wo + 32),
                            __builtin_amdgcn_mfma_f32_16x16x32_bf16(xf0,
                                *(const bf16x8*)(Wl_s + wo), z, 0, 0, 0), 0, 0, 0);
                accC[nt] = __builtin_amdgcn_mfma_f32_16x16x32_bf16(af1,
                            *(const bf16x8*)(Wc_s + wo + 32),
                            __builtin_amdgcn_mfma_f32_16x16x32_bf16(af0,
                                *(const bf16x8*)(Wc_s + wo), z, 0, 0, 0), 0, 0, 0);
            }
#pragma unroll
            for (int nt = 0; nt < 4; ++nt)
#pragma unroll
                for (int i = 0; i < 4; ++i)
                    tl[w][g * 4 + i][nt * 16 + cl] = f2bf(leaky(accC[nt][i]));
        }
        __syncthreads();
        if (active) {
            const bf16x8* tr = (const bf16x8*)&tl[w][cl][g * 8];
            bf16x8 tf0 = tr[0], tf1 = tr[4];
#pragma unroll
            for (int nt = 0; nt < 4; ++nt) {
                int wo = (nt * 16 + cl) * WS + g * 8;
                f32x4 z = (f32x4){0.f, 0.f, 0.f, 0.f};
                accG[nt] = __builtin_amdgcn_mfma_f32_16x16x32_bf16(tf1,
                            *(const bf16x8*)(Wg_s + wo + 32),
                            __builtin_amdgcn_mfma_f32_16x16x32_bf16(tf0,
                                *(const bf16x8*)(Wg_s + wo), z, 0, 0, 0), 0, 0, 0);
            }
#pragma unroll
            for (int nt = 0; nt < 4; ++nt) {
                int col = nt * 16 + cl;
#pragma unroll
                for (int i = 0; i < 4; ++i) {
                    size_t row = (size_t)(node0 + g * 4 + i);
                    float xh = leaky(accL[nt][i] + blv[nt]) + ID[row * D + col];
                    float o = leaky(accG[nt][i] + bgv[nt] + xh);
                    if (Ob) Ob[row * D + col] = f2bf(o);
                    else    Of[row * D + col] = o;
                }
            }
        }
        __syncthreads();
    }
}

extern "C" void kernel_launch(void* const* d_in, const int* in_sizes, int n_in,
                              void* d_out, int out_size, void* d_ws, size_t ws_size,
                              hipStream_t stream)
{
    const float* features = (const float*)d_in[0];
    const float* id_emb   = (const float*)d_in[1];
    const int*   eidx     = (const int*)d_in[2];
    const float* W_mlp    = (const float*)d_in[3];
    const float* b_mlp    = (const float*)d_in[4];
    const float* Wc1 = (const float*)d_in[5];
    const float* Wl1 = (const float*)d_in[6];
    const float* bl1 = (const float*)d_in[7];
    const float* Wg1 = (const float*)d_in[8];
    const float* bg1 = (const float*)d_in[9];
    const float* Wc2 = (const float*)d_in[10];
    const float* Wl2 = (const float*)d_in[11];
    const float* bl2 = (const float*)d_in[12];
    const float* Wg2 = (const float*)d_in[13];
    const float* bg2 = (const float*)d_in[14];

    int N = in_sizes[0] / D_FEAT;
    int E = in_sizes[2] / 2;
    const int* esrc = eidx;
    const int* edst = eidx + E;
    int nbk = (N + BW - 1) >> BSH;               // 782 for N=100000

    unsigned short* Xb = (unsigned short*)d_ws;  // [N][64] bf16
    unsigned short* Ab = Xb + (size_t)N * D;     // [N][64] bf16
    int* srcs   = (int*)(Ab + (size_t)N * D);    // [nbk*CAP] bucket-strided
    int2* rng   = (int2*)(srcs + (size_t)nbk * CAP);  // [N]
    int* gcur   = (int*)(rng + N);               // [1024]
    unsigned short* wt = (unsigned short*)(gcur + 1024);  // 8192 + 6*4096 bf16
    unsigned short* Wmt  = wt;
    unsigned short* Wct1 = wt + 8192;
    unsigned short* Wlt1 = Wct1 + 4096;
    unsigned short* Wgt1 = Wlt1 + 4096;
    unsigned short* Wct2 = Wgt1 + 4096;
    unsigned short* Wlt2 = Wct2 + 4096;
    unsigned short* Wgt2 = Wlt2 + 4096;
    unsigned char* Xf8 = (unsigned char*)(Wgt2 + 4096);   // [N][64] fp8

    // pairs scratch lives in d_out (25.6 MB >= nbk*CAP*4 = 8.0 MB); fully dead
    // before the final combine writes d_out.
    unsigned* pairs = (unsigned*)d_out;

    dim3 blk(256);
    int egrid = (E + 4095) / 4096;
    int cgrid = 782;                             // ~3 blocks/CU, 2 tiles each

    P7 p7;
    p7.w[0] = W_mlp; p7.w[1] = Wc1; p7.w[2] = Wl1; p7.w[3] = Wg1;
    p7.w[4] = Wc2; p7.w[5] = Wl2; p7.w[6] = Wg2;

    // weight transpose + gcur init (one dispatch)
    k_prep<<<8, blk, 0, stream>>>(p7, wt, gcur, nbk);

    // edge partition || MLP (independent -> one dispatch)
    k_partmlp<<<egrid + 512, blk, 0, stream>>>(esrc, edst, gcur, pairs, E, egrid,
                                               features, Wmt, b_mlp, Xb, Xf8, N);

    // per-bucket sort -> per-node CSR
    k_sort<<<nbk, blk, 0, stream>>>(pairs, gcur, rng, srcs, N);

    // layer 1: fp8 gather (x small after L2-norm -> negligible fp8 error)
    k_gather8<<<(N + 3) / 4, blk, 0, stream>>>(rng, srcs, Xf8, Ab, N);
    k_combine<<<cgrid, blk, 0, stream>>>(Xb, Ab, Wct1, Wlt1, bl1, Wgt1, bg1, id_emb,
                                         Xb, (float*)nullptr, N);

    // layer 2: bf16 gather (x1 is id_emb-dominated, fp8 too lossy)
    k_gather<<<(N + 3) / 4, blk, 0, stream>>>(rng, srcs, Xb, Ab, N);
    k_combine<<<cgrid, blk, 0, stream>>>(Xb, Ab, Wct2, Wlt2, bl2, Wgt2, bg2, id_emb,
                                         (unsigned short*)nullptr, (float*)d_out, N);
}